// Round 1
// baseline (154.047 us; speedup 1.0000x reference)
//
#include <hip/hip_runtime.h>
#include <math.h>

// Capsule routing, u_hat never materialized (factors through W):
//   v[b,n,c] = sum_i c[b,n,i] u[b,i,c]
//   s[b,n,d] = sum_c v[b,n,c] W[c,n*64+d];  o = squash(s)
//   t[b,n,c] = sum_d o[b,n,d] W[c,n*64+d]
//   b[b,n,i] = sum_c t[b,n,c] u[b,i,c]
// Iter 0: b=0 -> c uniform 1/32 -> v0 = colsum(u)/32.
//
// R10: precast u to bf16 (ub16, 16 MB) inside k_pre's colsum blocks (values
// already in registers there -> costs only coalesced stores). k_route loses
// ALL fp32->bf16 pack VALU (was ~160 VALU/lane in phase A + 32 in u_t
// staging, re-done twice per launch pair) and halves its u-stream bytes:
// phase A = one bf16x8 load per k0, u_t staging = straight bf16 copy.
// Numerics identical (same RNE pack, applied once instead of twice).
// Everything else carried from R9: bf16 W both layouts, bf16 pv partials,
// MFMA route structure, no grid.sync (R4: ~1000us spin).

constexpr int Bn = 32, In = 1024, Cn = 256, Nn = 32, Dn = 64, ND = 2048;

typedef __attribute__((ext_vector_type(8))) short bf16x8;
typedef __attribute__((ext_vector_type(4))) float f32x4;

__device__ __forceinline__ unsigned int packbf2(float a, float b) {
  unsigned int xa = __float_as_uint(a), xb = __float_as_uint(b);
  xa = (xa + 0x7fffu + ((xa >> 16) & 1u)) >> 16;  // RNE
  xb = (xb + 0x7fffu + ((xb >> 16) & 1u)) >> 16;
  return xa | (xb << 16);
}
__device__ __forceinline__ unsigned short packbf1(float a) {
  unsigned int x = __float_as_uint(a);
  return (unsigned short)((x + 0x7fffu + ((x >> 16) & 1u)) >> 16);
}
__device__ __forceinline__ float bfu(unsigned short us) {
  return __uint_as_float((unsigned int)us << 16);
}

// ---- k_pre: colsum+ucast (z<1024) | WbfT transpose (1024..1151) | Wbf cast -
__global__ __launch_bounds__(256) void k_pre(
    const float* __restrict__ u, const float* __restrict__ W,
    float* __restrict__ psu, unsigned short* __restrict__ Wbf,
    unsigned short* __restrict__ WbfT, unsigned short* __restrict__ ub16) {
  const int z = blockIdx.x, tid = threadIdx.x;
  if (z < 1024) {  // colsum: psu[z*256+c] = sum over 32 i of u[b, ch*32+i, c]
    int b = z >> 5, ch = z & 31;
    const float* up = u + ((size_t)(b * In + ch * 32)) * Cn + tid;
    unsigned short* ubp = ub16 + ((size_t)(b * In + ch * 32)) * Cn + tid;
    float s = 0.f;
#pragma unroll 8
    for (int j = 0; j < 32; ++j) {
      float v = up[(size_t)j * Cn];
      s += v;
      ubp[(size_t)j * Cn] = packbf1(v);  // bf16 u copy, coalesced 512B rows
    }
    psu[(size_t)z * Cn + tid] = s;
  } else if (z < 1152) {  // WbfT[nd][c] = bf16(W[c][nd]), 64x64 tiles
    __shared__ float tile[64][65];
    int t = z - 1024;
    int x0 = (t & 31) * 64, y0 = (t >> 5) * 64;  // x=nd, y=c
    int lx = tid & 63, ly = tid >> 6;
#pragma unroll
    for (int k = 0; k < 16; ++k) {
      int y = ly + k * 4;
      tile[y][lx] = W[(size_t)(y0 + y) * ND + x0 + lx];
    }
    __syncthreads();
#pragma unroll
    for (int k = 0; k < 8; ++k) {  // 64 rows x 32 uints
      int idx = tid + k * 256;
      int row = idx >> 5, cu = idx & 31;
      unsigned int v = packbf2(tile[2 * cu][row], tile[2 * cu + 1][row]);
      *(unsigned int*)&WbfT[(size_t)(x0 + row) * Cn + y0 + 2 * cu] = v;
    }
  } else {  // Wbf: straight cast, 128 blocks x 4096 floats
    int zb = z - 1152;
    const float* src = W + (size_t)zb * 4096;
    unsigned short* dst = Wbf + (size_t)zb * 4096;
#pragma unroll
    for (int k = 0; k < 4; ++k) {
      int off = k * 1024 + tid * 4;
      const float4 v = *(const float4*)&src[off];
      *(uint2*)&dst[off] = make_uint2(packbf2(v.x, v.y), packbf2(v.z, v.w));
    }
  }
}

// ---- fused: v-reduce -> s -> squash -> [out] -> [t]; W read from L2/L3 -----
__global__ __launch_bounds__(256) void k_sst(
    const void* __restrict__ src, int srcBf16, int count, long bS, long nS,
    long cS, float scale, const unsigned short* __restrict__ Wbf,
    const unsigned short* __restrict__ WbfT, float* __restrict__ tb,
    float* __restrict__ outp, int writeT) {
  int bn = blockIdx.x, b = bn >> 5, n = bn & 31;
  int tid = threadIdx.x;
  __shared__ float vs[Cn];
  __shared__ float red[Cn];
  __shared__ float ol[Dn];
  {  // v-reduce (lanes = c, coalesced)
    float s = 0.f;
    if (srcBf16) {
      const unsigned short* p = (const unsigned short*)src + b * bS + n * nS + tid;
      for (int ch = 0; ch < count; ++ch) s += bfu(p[(size_t)ch * cS]);
    } else {
      const float* p = (const float*)src + b * bS + n * nS + tid;
      for (int ch = 0; ch < count; ++ch) s += p[(size_t)ch * cS];
    }
    vs[tid] = s * scale;
  }
  __syncthreads();
  {  // s partials: thread (q = tid>>6, d = tid&63); Wbf rows 128 B coalesced
    int q = tid >> 6, d = tid & 63;
    const unsigned short* wp = Wbf + (size_t)(q * 64) * ND + (size_t)n * Dn + d;
    float a = 0.f;
#pragma unroll 8
    for (int c2 = 0; c2 < 64; ++c2) a += vs[q * 64 + c2] * bfu(wp[(size_t)c2 * ND]);
    red[tid] = a;
  }
  __syncthreads();
  if (tid < 64) {  // squash (one full wave)
    float a = red[tid] + red[64 + tid] + red[128 + tid] + red[192 + tid];
    float sq = a * a;
#pragma unroll
    for (int off = 32; off > 0; off >>= 1) sq += __shfl_xor(sq, off, 64);
    float o = a / sqrtf(sq + 1e-7f);
    ol[tid] = o;
    if (outp) outp[(size_t)bn * Dn + tid] = o;
  }
  __syncthreads();
  if (writeT) {  // t[c] = sum_d ol[d] * WbfT[n*64+d][c]; 512 B coalesced rows
    const unsigned short* wt = WbfT + (size_t)(n * Dn) * Cn + tid;
    float a = 0.f;
#pragma unroll 8
    for (int d2 = 0; d2 < 64; ++d2) a += ol[d2] * bfu(wt[(size_t)d2 * Cn]);
    tb[(size_t)bn * Cn + tid] = a;
  }
}

// ---- fused routing step (MFMA): bb = u.t^T -> softmax -> pv = c.u ----------
// Block (b, it): i-tile of 32, 256 threads (4 waves). pv stored bf16.
// u consumed as pre-cast bf16 (ub16) -> no pack VALU in this kernel.
__global__ __launch_bounds__(256, 4) void k_route(
    const float* __restrict__ tb, const unsigned short* __restrict__ ub16,
    unsigned short* __restrict__ pvb) {
  const int b = blockIdx.x, itile = blockIdx.y, i0 = itile * 32;
  const int tid = threadIdx.x;
  const int lane = tid & 63, w = tid >> 6;
  const int mrow = lane & 15, quad = lane >> 4;

  __shared__ unsigned short t_l[32][264];   // bf16; row 528 B (16B-mult)
  __shared__ unsigned short u_t[256][40];   // bf16 i-major; row 80 B
  __shared__ unsigned short cm_l[32][40];   // bf16 softmax(c)
  __shared__ float bb_l[32][36];

  // ---- stage t (coalesced, packed here) + u_t (bf16 copy, transposed) ----
  {
    const float* tp = tb + (size_t)b * Nn * Cn;
#pragma unroll
    for (int k = 0; k < 8; ++k) {
      int idx = tid + k * 256;           // 2048 = 32 rows x 64 quads
      int row = idx >> 6, q = idx & 63;
      const float4 tv = *(const float4*)&tp[(size_t)row * Cn + q * 4];
      *(uint2*)&t_l[row][q * 4] =
          make_uint2(packbf2(tv.x, tv.y), packbf2(tv.z, tv.w));
    }
    const int ti = tid & 31, qb = tid >> 5;
    const unsigned short* up = ub16 + ((size_t)(b * In + i0 + ti)) * Cn;
#pragma unroll
    for (int m = 0; m < 4; ++m) {
      int c8 = qb + m * 8;               // chunk of 8 consecutive c
      union { bf16x8 v; unsigned short us[8]; } uv;
      uv.v = *(const bf16x8*)&up[c8 * 8];
#pragma unroll
      for (int e = 0; e < 8; ++e) u_t[c8 * 8 + e][ti] = uv.us[e];
    }
  }
  __syncthreads();

  // ---- phase A: D[i,n] = sum_c u[i,c] t[n,c]; wave tile (i0t, n0t) ----
  {
    const int i0t = (w & 1) * 16, n0t = (w >> 1) * 16;
    const unsigned short* ubp =
        ub16 + ((size_t)(b * In + i0 + i0t + mrow)) * Cn + quad * 8;
    f32x4 acc = {0.f, 0.f, 0.f, 0.f};
#pragma unroll
    for (int k0 = 0; k0 < 8; ++k0) {       // c = k0*32 + quad*8 + j
      const bf16x8 af = *(const bf16x8*)(ubp + k0 * 32);
      const bf16x8 bf = *(const bf16x8*)&t_l[n0t + mrow][k0 * 32 + quad * 8];
      acc = __builtin_amdgcn_mfma_f32_16x16x32_bf16(af, bf, acc, 0, 0, 0);
    }
    // D: col=lane&15 -> n within tile, row=quad*4+reg -> i within tile
#pragma unroll
    for (int r = 0; r < 4; ++r)
      bb_l[n0t + mrow][i0t + quad * 4 + r] = acc[r];
  }
  __syncthreads();

  // ---- softmax over n per i ----
  if (tid < 32) {
    float m = -1e30f;
#pragma unroll
    for (int n = 0; n < Nn; ++n) m = fmaxf(m, bb_l[n][tid]);
    float e[Nn];
    float ssum = 0.f;
#pragma unroll
    for (int n = 0; n < Nn; ++n) { e[n] = __expf(bb_l[n][tid] - m); ssum += e[n]; }
    float inv = 1.f / ssum;
#pragma unroll
    for (int n = 0; n < Nn; ++n) bb_l[n][tid] = e[n] * inv;
  }
  __syncthreads();

  // ---- pack c to bf16 (cm_l), 256 threads x 4 elems ----
  {
    int n = tid >> 3, q = tid & 7;
    const float4 cv = *(const float4*)&bb_l[n][q * 4];
    *(uint2*)&cm_l[n][q * 4] = make_uint2(packbf2(cv.x, cv.y), packbf2(cv.z, cv.w));
  }
  __syncthreads();

  // ---- phase B: D[n,c] = sum_i c[n,i] u[i,c]; K=32 -> 1 MFMA/tile ----
  {
    const int mt = w & 1;                  // ncap tile (0..1)
    const bf16x8 af = *(const bf16x8*)&cm_l[mt * 16 + mrow][quad * 8];
#pragma unroll
    for (int j = 0; j < 8; ++j) {
      const int ct = (w >> 1) * 8 + j;     // c tile (0..15)
      const bf16x8 bf = *(const bf16x8*)&u_t[ct * 16 + mrow][quad * 8];
      f32x4 d = {0.f, 0.f, 0.f, 0.f};
      d = __builtin_amdgcn_mfma_f32_16x16x32_bf16(af, bf, d, 0, 0, 0);
      // D: col=lane&15 -> c within tile, row=quad*4+reg -> ncap within tile
#pragma unroll
      for (int r = 0; r < 4; ++r)
        pvb[((size_t)((b * 32 + itile) * Nn + mt * 16 + quad * 4 + r)) * Cn +
            ct * 16 + mrow] = packbf1(d[r]);
    }
  }
}

extern "C" void kernel_launch(void* const* d_in, const int* in_sizes, int n_in,
                              void* d_out, int out_size, void* d_ws, size_t ws_size,
                              hipStream_t stream) {
  (void)in_sizes; (void)n_in; (void)out_size; (void)ws_size;
  const float* u = (const float*)d_in[0];   // (32,1024,256)
  const float* W = (const float*)d_in[1];   // (256,2048)
  float* out = (float*)d_out;               // (32,32,64)
  float* ws = (float*)d_ws;
  // ws layout (float units): pvb bf16 8388608 ush = 4194304 | psu 262144 |
  // Wbf 524288 ush = 262144 | WbfT 262144 | tb 262144 |
  // ub16 bf16 8388608 ush = 4194304  => 36 MB total.
  unsigned short* pvb  = (unsigned short*)ws;
  float*          psu  = ws + 4194304;
  unsigned short* Wbf  = (unsigned short*)(ws + 4456448);
  unsigned short* WbfT = (unsigned short*)(ws + 4718592);
  float*          tbb  = ws + 4980736;
  unsigned short* ub16 = (unsigned short*)(ws + 5242880);

  k_pre<<<1280, 256, 0, stream>>>(u, W, psu, Wbf, WbfT, ub16);
  // iter 0: v0 = colsum/32 (psu fp32: b-stride 8192, ch-stride 256)
  k_sst<<<1024, 256, 0, stream>>>(psu, 0, 32, 8192L, 0L, 256L, 1.0f / 32.0f,
                                  Wbf, WbfT, tbb, nullptr, 1);
  // iter 1
  k_route<<<dim3(32, 32), 256, 0, stream>>>(tbb, ub16, pvb);
  // pvb bf16: b-stride 262144, n-stride 256, it-stride 8192 (ushort units)
  k_sst<<<1024, 256, 0, stream>>>(pvb, 1, 32, 262144L, 256L, 8192L, 1.0f,
                                  Wbf, WbfT, tbb, nullptr, 1);
  // iter 2 (final)
  k_route<<<dim3(32, 32), 256, 0, stream>>>(tbb, ub16, pvb);
  k_sst<<<1024, 256, 0, stream>>>(pvb, 1, 32, 262144L, 256L, 8192L, 1.0f,
                                  Wbf, WbfT, tbb, out, 0);
}

// Round 2
// 126.763 us; speedup vs baseline: 1.2152x; 1.2152x over previous
//
#include <hip/hip_runtime.h>
#include <math.h>

// Capsule routing, u_hat never materialized (factors through W):
//   v[b,n,c] = sum_i c[b,n,i] u[b,i,c]
//   s[b,n,d] = sum_c v[b,n,c] W[c,n*64+d];  o = squash(s)
//   t[b,n,c] = sum_d o[b,n,d] W[c,n*64+d]
//   b[b,n,i] = sum_c t[b,n,c] u[b,i,c]
// Iter 0: b=0 -> c uniform 1/32 -> v0 = colsum(u)/32.
//
// R11: latency round. Counters showed all kernels < 42us with total 154us vs
// ~60us of BW-obligatory work -> issue/latency bound, not BW bound.
//  - k_sst: VMEM/thread 160 -> 20. All three dot phases now bf16x8/float4
//    vector loads + LDS partial trees, compile-time unrolled (count=32 was a
//    runtime bound before -> no unroll, no load pipelining).
//  - t buffer now bf16 (k_sst packs on store; k_route stages with straight
//    copy, no pack VALU, half the L2 bytes).
//  - k_route: wave-parallel softmax (256 thr, depth ~30 vs ~100 serial on 32
//    thr; kills the 32-float e[] register array). Phase-B pv stores staged
//    through LDS (reuse t_l) -> 4x16B coalesced stores vs 32x2B scattered.
// Carried: ub16 precast (R10), bf16 W both layouts, bf16 pv partials, MFMA
// route structure, no grid.sync (R4: ~1000us spin).

constexpr int Bn = 32, In = 1024, Cn = 256, Nn = 32, Dn = 64, ND = 2048;

typedef __attribute__((ext_vector_type(8))) short bf16x8;
typedef __attribute__((ext_vector_type(4))) float f32x4;

__device__ __forceinline__ unsigned int packbf2(float a, float b) {
  unsigned int xa = __float_as_uint(a), xb = __float_as_uint(b);
  xa = (xa + 0x7fffu + ((xa >> 16) & 1u)) >> 16;  // RNE
  xb = (xb + 0x7fffu + ((xb >> 16) & 1u)) >> 16;
  return xa | (xb << 16);
}
__device__ __forceinline__ unsigned short packbf1(float a) {
  unsigned int x = __float_as_uint(a);
  return (unsigned short)((x + 0x7fffu + ((x >> 16) & 1u)) >> 16);
}
__device__ __forceinline__ float bfu(unsigned short us) {
  return __uint_as_float((unsigned int)us << 16);
}

// ---- k_pre: colsum+ucast (z<1024) | WbfT transpose (1024..1151) | Wbf cast -
__global__ __launch_bounds__(256) void k_pre(
    const float* __restrict__ u, const float* __restrict__ W,
    float* __restrict__ psu, unsigned short* __restrict__ Wbf,
    unsigned short* __restrict__ WbfT, unsigned short* __restrict__ ub16) {
  const int z = blockIdx.x, tid = threadIdx.x;
  if (z < 1024) {  // colsum: psu[z*256+c] = sum over 32 i of u[b, ch*32+i, c]
    int b = z >> 5, ch = z & 31;
    const float* up = u + ((size_t)(b * In + ch * 32)) * Cn + tid;
    unsigned short* ubp = ub16 + ((size_t)(b * In + ch * 32)) * Cn + tid;
    float s = 0.f;
#pragma unroll 8
    for (int j = 0; j < 32; ++j) {
      float v = up[(size_t)j * Cn];
      s += v;
      ubp[(size_t)j * Cn] = packbf1(v);  // bf16 u copy, coalesced 512B rows
    }
    psu[(size_t)z * Cn + tid] = s;
  } else if (z < 1152) {  // WbfT[nd][c] = bf16(W[c][nd]), 64x64 tiles
    __shared__ float tile[64][65];
    int t = z - 1024;
    int x0 = (t & 31) * 64, y0 = (t >> 5) * 64;  // x=nd, y=c
    int lx = tid & 63, ly = tid >> 6;
#pragma unroll
    for (int k = 0; k < 16; ++k) {
      int y = ly + k * 4;
      tile[y][lx] = W[(size_t)(y0 + y) * ND + x0 + lx];
    }
    __syncthreads();
#pragma unroll
    for (int k = 0; k < 8; ++k) {  // 64 rows x 32 uints
      int idx = tid + k * 256;
      int row = idx >> 5, cu = idx & 31;
      unsigned int v = packbf2(tile[2 * cu][row], tile[2 * cu + 1][row]);
      *(unsigned int*)&WbfT[(size_t)(x0 + row) * Cn + y0 + 2 * cu] = v;
    }
  } else {  // Wbf: straight cast, 128 blocks x 4096 floats
    int zb = z - 1152;
    const float* src = W + (size_t)zb * 4096;
    unsigned short* dst = Wbf + (size_t)zb * 4096;
#pragma unroll
    for (int k = 0; k < 4; ++k) {
      int off = k * 1024 + tid * 4;
      const float4 v = *(const float4*)&src[off];
      *(uint2*)&dst[off] = make_uint2(packbf2(v.x, v.y), packbf2(v.z, v.w));
    }
  }
}

// ---- fused: v-reduce -> s -> squash -> [out] -> [t]; vectorized loads ------
// count fixed at 32. Thread maps per phase; LDS partial trees between.
__global__ __launch_bounds__(256) void k_sst(
    const void* __restrict__ src, int srcBf16, long bS, long nS, long cS,
    float scale, const unsigned short* __restrict__ Wbf,
    const unsigned short* __restrict__ WbfT, unsigned short* __restrict__ tb,
    float* __restrict__ outp, int writeT) {
  int bn = blockIdx.x, b = bn >> 5, n = bn & 31;
  int tid = threadIdx.x;
  __shared__ float vs[Cn];
  __shared__ float ol[Dn];
  __shared__ float scr[2176];  // phase1/3: [8][272]; phase2: [32][68]
  {  // phase 1a: v partials. thread (g=tid>>5 -> 4 ch, co=tid&31 -> 8 c)
    const int g = tid >> 5, co = tid & 31;
    float acc[8];
#pragma unroll
    for (int e = 0; e < 8; ++e) acc[e] = 0.f;
    if (srcBf16) {
      const unsigned short* p =
          (const unsigned short*)src + b * bS + n * nS + co * 8;
#pragma unroll
      for (int k = 0; k < 4; ++k) {
        union { bf16x8 v; unsigned short us[8]; } w;
        w.v = *(const bf16x8*)&p[(size_t)(g * 4 + k) * cS];
#pragma unroll
        for (int e = 0; e < 8; ++e) acc[e] += bfu(w.us[e]);
      }
    } else {
      const float* p = (const float*)src + b * bS + n * nS + co * 8;
#pragma unroll
      for (int k = 0; k < 4; ++k) {
        const float4 v0 = *(const float4*)&p[(size_t)(g * 4 + k) * cS];
        const float4 v1 = *(const float4*)&p[(size_t)(g * 4 + k) * cS + 4];
        acc[0] += v0.x; acc[1] += v0.y; acc[2] += v0.z; acc[3] += v0.w;
        acc[4] += v1.x; acc[5] += v1.y; acc[6] += v1.z; acc[7] += v1.w;
      }
    }
    *(float4*)&scr[g * 272 + co * 8] =
        make_float4(acc[0], acc[1], acc[2], acc[3]);
    *(float4*)&scr[g * 272 + co * 8 + 4] =
        make_float4(acc[4], acc[5], acc[6], acc[7]);
  }
  __syncthreads();
  {  // phase 1b: vs[c] = sum of 8 partials
    float s = 0.f;
#pragma unroll
    for (int k = 0; k < 8; ++k) s += scr[k * 272 + tid];
    vs[tid] = s * scale;
  }
  __syncthreads();
  {  // phase 2: s partials. thread (cg=tid>>3 -> 8 c, do8=tid&7 -> 8 d)
    const int cg = tid >> 3, do8 = tid & 7;
    const unsigned short* wp =
        Wbf + (size_t)(cg * 8) * ND + (size_t)n * Dn + do8 * 8;
    float acc[8];
#pragma unroll
    for (int e = 0; e < 8; ++e) acc[e] = 0.f;
#pragma unroll
    for (int j = 0; j < 8; ++j) {
      union { bf16x8 v; unsigned short us[8]; } w;
      w.v = *(const bf16x8*)&wp[(size_t)j * ND];
      const float vc = vs[cg * 8 + j];
#pragma unroll
      for (int e = 0; e < 8; ++e) acc[e] += vc * bfu(w.us[e]);
    }
    *(float4*)&scr[cg * 68 + do8 * 8] =
        make_float4(acc[0], acc[1], acc[2], acc[3]);
    *(float4*)&scr[cg * 68 + do8 * 8 + 4] =
        make_float4(acc[4], acc[5], acc[6], acc[7]);
  }
  __syncthreads();
  if (tid < 64) {  // squash (one full wave): sum 32 cg partials per d
    float a = 0.f;
#pragma unroll
    for (int k = 0; k < 32; ++k) a += scr[k * 68 + tid];
    float sq = a * a;
#pragma unroll
    for (int off = 32; off > 0; off >>= 1) sq += __shfl_xor(sq, off, 64);
    float o = a / sqrtf(sq + 1e-7f);
    ol[tid] = o;
    if (outp) outp[(size_t)bn * Dn + tid] = o;
  }
  __syncthreads();
  if (writeT) {  // phase 3: t partials. thread (dg=tid>>5 -> 8 d, co -> 8 c)
    {
      const int dg = tid >> 5, co = tid & 31;
      const unsigned short* wt =
          WbfT + (size_t)(n * Dn + dg * 8) * Cn + co * 8;
      float acc[8];
#pragma unroll
      for (int e = 0; e < 8; ++e) acc[e] = 0.f;
#pragma unroll
      for (int e = 0; e < 8; ++e) {
        union { bf16x8 v; unsigned short us[8]; } w;
        w.v = *(const bf16x8*)&wt[(size_t)e * Cn];
        const float od = ol[dg * 8 + e];
#pragma unroll
        for (int cc = 0; cc < 8; ++cc) acc[cc] += od * bfu(w.us[cc]);
      }
      *(float4*)&scr[dg * 272 + co * 8] =
          make_float4(acc[0], acc[1], acc[2], acc[3]);
      *(float4*)&scr[dg * 272 + co * 8 + 4] =
          make_float4(acc[4], acc[5], acc[6], acc[7]);
    }
    __syncthreads();
    {
      float s = 0.f;
#pragma unroll
      for (int k = 0; k < 8; ++k) s += scr[k * 272 + tid];
      tb[(size_t)bn * Cn + tid] = packbf1(s);  // t stored bf16
    }
  }
}

// ---- fused routing step (MFMA): bb = u.t^T -> softmax -> pv = c.u ----------
// Block (b, it): i-tile of 32, 256 threads (4 waves). pv stored bf16.
// t arrives pre-cast bf16; u consumed as pre-cast bf16 (ub16).
__global__ __launch_bounds__(256, 4) void k_route(
    const unsigned short* __restrict__ tbb,
    const unsigned short* __restrict__ ub16,
    unsigned short* __restrict__ pvb) {
  const int b = blockIdx.x, itile = blockIdx.y, i0 = itile * 32;
  const int tid = threadIdx.x;
  const int lane = tid & 63, w = tid >> 6;
  const int mrow = lane & 15, quad = lane >> 4;

  __shared__ unsigned short t_l[32][264];   // bf16; row 528 B; reused as pvs
  __shared__ unsigned short u_t[256][40];   // bf16 i-major; row 80 B
  __shared__ unsigned short cm_l[32][40];   // bf16 softmax(c)
  __shared__ float bb_l[32][36];
  __shared__ float smr[2][8][32];           // softmax partial max / sum

  // ---- stage t (straight bf16 copy) + u_t (bf16 copy, transposed) ----
  {
    const unsigned short* tp = tbb + (size_t)b * Nn * Cn;
#pragma unroll
    for (int k = 0; k < 8; ++k) {
      int idx = tid + k * 256;           // 2048 = 32 rows x 64 quads
      int row = idx >> 6, q = idx & 63;
      *(uint2*)&t_l[row][q * 4] = *(const uint2*)&tp[(size_t)row * Cn + q * 4];
    }
    const int ti = tid & 31, qb = tid >> 5;
    const unsigned short* up = ub16 + ((size_t)(b * In + i0 + ti)) * Cn;
#pragma unroll
    for (int m = 0; m < 4; ++m) {
      int c8 = qb + m * 8;               // chunk of 8 consecutive c
      union { bf16x8 v; unsigned short us[8]; } uv;
      uv.v = *(const bf16x8*)&up[c8 * 8];
#pragma unroll
      for (int e = 0; e < 8; ++e) u_t[c8 * 8 + e][ti] = uv.us[e];
    }
  }
  __syncthreads();

  // ---- phase A: D[i,n] = sum_c u[i,c] t[n,c]; wave tile (i0t, n0t) ----
  {
    const int i0t = (w & 1) * 16, n0t = (w >> 1) * 16;
    const unsigned short* ubp =
        ub16 + ((size_t)(b * In + i0 + i0t + mrow)) * Cn + quad * 8;
    f32x4 acc = {0.f, 0.f, 0.f, 0.f};
#pragma unroll
    for (int k0 = 0; k0 < 8; ++k0) {       // c = k0*32 + quad*8 + j
      const bf16x8 af = *(const bf16x8*)(ubp + k0 * 32);
      const bf16x8 bf = *(const bf16x8*)&t_l[n0t + mrow][k0 * 32 + quad * 8];
      acc = __builtin_amdgcn_mfma_f32_16x16x32_bf16(af, bf, acc, 0, 0, 0);
    }
    // D: col=lane&15 -> n within tile, row=quad*4+reg -> i within tile
#pragma unroll
    for (int r = 0; r < 4; ++r)
      bb_l[n0t + mrow][i0t + quad * 4 + r] = acc[r];
  }
  __syncthreads();

  // ---- softmax over n per i (wave-parallel: thread (g=tid>>5, i=tid&31)) --
  {
    const int i = tid & 31, g = tid >> 5;  // g handles n = g*4 .. g*4+3
    float m4 = bb_l[g * 4 + 0][i];
    m4 = fmaxf(m4, bb_l[g * 4 + 1][i]);
    m4 = fmaxf(m4, bb_l[g * 4 + 2][i]);
    m4 = fmaxf(m4, bb_l[g * 4 + 3][i]);
    smr[0][g][i] = m4;
    __syncthreads();
    float m = smr[0][0][i];
#pragma unroll
    for (int k = 1; k < 8; ++k) m = fmaxf(m, smr[0][k][i]);
    float s4 = 0.f;
#pragma unroll
    for (int r = 0; r < 4; ++r) {
      float e = __expf(bb_l[g * 4 + r][i] - m);
      bb_l[g * 4 + r][i] = e;
      s4 += e;
    }
    smr[1][g][i] = s4;
    __syncthreads();
    float ss = 0.f;
#pragma unroll
    for (int k = 0; k < 8; ++k) ss += smr[1][k][i];
    float inv = 1.f / ss;
#pragma unroll
    for (int r = 0; r < 4; ++r) bb_l[g * 4 + r][i] *= inv;
  }
  __syncthreads();

  // ---- pack c to bf16 (cm_l), 256 threads x 4 elems ----
  {
    int n = tid >> 3, q = tid & 7;
    const float4 cv = *(const float4*)&bb_l[n][q * 4];
    *(uint2*)&cm_l[n][q * 4] = make_uint2(packbf2(cv.x, cv.y), packbf2(cv.z, cv.w));
  }
  __syncthreads();

  // ---- phase B: D[n,c] = sum_i c[n,i] u[i,c]; K=32 -> 1 MFMA/tile ----
  // Output staged in LDS (reuse t_l as pvs[32][264]) then coalesced store.
  unsigned short* pvs = &t_l[0][0];
  {
    const int mt = w & 1;                  // ncap tile (0..1)
    const bf16x8 af = *(const bf16x8*)&cm_l[mt * 16 + mrow][quad * 8];
#pragma unroll
    for (int j = 0; j < 8; ++j) {
      const int ct = (w >> 1) * 8 + j;     // c tile (0..15)
      const bf16x8 bfv = *(const bf16x8*)&u_t[ct * 16 + mrow][quad * 8];
      f32x4 d = {0.f, 0.f, 0.f, 0.f};
      d = __builtin_amdgcn_mfma_f32_16x16x32_bf16(af, bfv, d, 0, 0, 0);
      // D: col=lane&15 -> c within tile, row=quad*4+reg -> ncap within tile
#pragma unroll
      for (int r = 0; r < 4; ++r)
        pvs[(size_t)(mt * 16 + quad * 4 + r) * 264 + ct * 16 + mrow] =
            packbf1(d[r]);
    }
  }
  __syncthreads();
  {  // coalesced pvb store: thread (rg=tid>>5, co=tid&31); rows rg+8k
    unsigned short* pb = pvb + (size_t)((b * 32 + itile) * Nn) * Cn;
    const int rg = tid >> 5, co = tid & 31;
#pragma unroll
    for (int k = 0; k < 4; ++k) {
      int row = rg + k * 8;
      const uint4 v = *(const uint4*)&pvs[(size_t)row * 264 + co * 8];
      *(uint4*)&pb[(size_t)row * Cn + co * 8] = v;
    }
  }
}

extern "C" void kernel_launch(void* const* d_in, const int* in_sizes, int n_in,
                              void* d_out, int out_size, void* d_ws, size_t ws_size,
                              hipStream_t stream) {
  (void)in_sizes; (void)n_in; (void)out_size; (void)ws_size;
  const float* u = (const float*)d_in[0];   // (32,1024,256)
  const float* W = (const float*)d_in[1];   // (256,2048)
  float* out = (float*)d_out;               // (32,32,64)
  float* ws = (float*)d_ws;
  // ws layout (float units): pvb bf16 8388608 ush = 4194304 | psu 262144 |
  // Wbf 524288 ush = 262144 | WbfT 262144 | tbb16 bf16 (131072 used of
  // 262144 slot) | ub16 bf16 8388608 ush = 4194304  => 36 MB total.
  unsigned short* pvb  = (unsigned short*)ws;
  float*          psu  = ws + 4194304;
  unsigned short* Wbf  = (unsigned short*)(ws + 4456448);
  unsigned short* WbfT = (unsigned short*)(ws + 4718592);
  unsigned short* tb16 = (unsigned short*)(ws + 4980736);
  unsigned short* ub16 = (unsigned short*)(ws + 5242880);

  k_pre<<<1280, 256, 0, stream>>>(u, W, psu, Wbf, WbfT, ub16);
  // iter 0: v0 = colsum/32 (psu fp32: b-stride 8192, ch-stride 256)
  k_sst<<<1024, 256, 0, stream>>>(psu, 0, 8192L, 0L, 256L, 1.0f / 32.0f,
                                  Wbf, WbfT, tb16, nullptr, 1);
  // iter 1
  k_route<<<dim3(32, 32), 256, 0, stream>>>(tb16, ub16, pvb);
  // pvb bf16: b-stride 262144, n-stride 256, ch(it)-stride 8192 (ushorts)
  k_sst<<<1024, 256, 0, stream>>>(pvb, 1, 262144L, 256L, 8192L, 1.0f,
                                  Wbf, WbfT, tb16, nullptr, 1);
  // iter 2 (final)
  k_route<<<dim3(32, 32), 256, 0, stream>>>(tb16, ub16, pvb);
  k_sst<<<1024, 256, 0, stream>>>(pvb, 1, 262144L, 256L, 8192L, 1.0f,
                                  Wbf, WbfT, tb16, out, 0);
}